// Round 1
// baseline (470.498 us; speedup 1.0000x reference)
//
#include <hip/hip_runtime.h>
#include <hip/hip_bf16.h>
#include <stdint.h>

// SelfAttentionHead: B=4, T=4096, C=1024, D=128, fp32 in/out.
// Pipeline: wcvt (W->bf16 transposed) -> proj (fused QKV MFMA GEMM, bf16 out,
// V transposed) -> attn (flash attention, kv-split=2, partials) -> merge.

typedef __attribute__((ext_vector_type(4))) float f32x4;
typedef __attribute__((ext_vector_type(8))) short bf16x8;
typedef __attribute__((ext_vector_type(4))) unsigned short u16x4;

#define NBATCH 4
#define NT 4096
#define NC 1024
#define ND 128
#define BT (NBATCH * NT)   // 16384
#define KHALF 2048         // kv split point

__device__ __forceinline__ unsigned short f2bf(float f) {
  union { float f; uint32_t u; } v; v.f = f;
  uint32_t u = v.u;
  return (unsigned short)((u + 0x7FFFu + ((u >> 16) & 1u)) >> 16);
}

__device__ __forceinline__ bf16x8 cvt8(const f32x4 a0, const f32x4 a1) {
  bf16x8 r;
  r[0] = (short)f2bf(a0[0]); r[1] = (short)f2bf(a0[1]);
  r[2] = (short)f2bf(a0[2]); r[3] = (short)f2bf(a0[3]);
  r[4] = (short)f2bf(a1[0]); r[5] = (short)f2bf(a1[1]);
  r[6] = (short)f2bf(a1[2]); r[7] = (short)f2bf(a1[3]);
  return r;
}

// ---------------------------------------------------------------------------
// Kernel 1: convert Wq/Wk/Wv [C][D] fp32 -> Wt [3][D][C] bf16 (transposed)
// ---------------------------------------------------------------------------
__global__ void wcvt_kernel(const float* __restrict__ Wq, const float* __restrict__ Wk,
                            const float* __restrict__ Wv, unsigned short* __restrict__ Wt) {
  int idx = blockIdx.x * blockDim.x + threadIdx.x;  // [0, 3*128*1024)
  int m = idx >> 17;          // /131072
  int r = idx & 131071;
  int d = r >> 10;            // /1024
  int c = r & 1023;
  const float* W = (m == 0) ? Wq : (m == 1) ? Wk : Wv;
  Wt[idx] = f2bf(W[c * ND + d]);
}

// ---------------------------------------------------------------------------
// Kernel 2: fused QKV projection. Block = 256 threads (4 waves), M-tile = 64.
// Each wave: 16 rows x 384 cols (24 n-tiles of 16). K-step 32.
// Outputs: Qb,Kb bf16 [b*t][d]; Vt bf16 [b][d][t].
// ---------------------------------------------------------------------------
__global__ void proj_kernel(const float* __restrict__ x, const unsigned short* __restrict__ Wt,
                            unsigned short* __restrict__ Qb, unsigned short* __restrict__ Kb,
                            unsigned short* __restrict__ Vt) {
  int mrow0 = blockIdx.x * 64;
  int wave = threadIdx.x >> 6;
  int lane = threadIdx.x & 63;
  int r16 = lane & 15;
  int h4 = lane >> 4;
  int h8 = h4 * 8;

  int arow = mrow0 + wave * 16 + r16;      // A-fragment row (global b*t)
  const float* xr = x + (size_t)arow * NC;

  f32x4 acc[24];
  #pragma unroll
  for (int i = 0; i < 24; ++i) acc[i] = (f32x4){0.f, 0.f, 0.f, 0.f};

  for (int c0 = 0; c0 < NC; c0 += 32) {
    const f32x4 a0 = *(const f32x4*)(xr + c0 + h8);
    const f32x4 a1 = *(const f32x4*)(xr + c0 + h8 + 4);
    bf16x8 af = cvt8(a0, a1);
    #pragma unroll
    for (int nt = 0; nt < 24; ++nt) {
      // nt = m*8 + dt ; B-frag: rows of Wt[m][dt*16 + r16][c0 + h8 ..]
      const unsigned short* wrow = Wt + (size_t)nt * 16 * NC + (size_t)r16 * NC + c0 + h8;
      bf16x8 bfr = *(const bf16x8*)wrow;
      acc[nt] = __builtin_amdgcn_mfma_f32_16x16x32_bf16(af, bfr, acc[nt], 0, 0, 0);
    }
  }

  // C layout: col = lane&15 (d within tile), row = (lane>>4)*4 + reg (t within 16)
  // Q, K: [t][d] scattered ushort stores
  #pragma unroll
  for (int m = 0; m < 2; ++m) {
    unsigned short* dst = (m == 0) ? Qb : Kb;
    #pragma unroll
    for (int dt = 0; dt < 8; ++dt) {
      #pragma unroll
      for (int r = 0; r < 4; ++r) {
        int t = mrow0 + wave * 16 + h4 * 4 + r;
        dst[(size_t)t * ND + dt * 16 + r16] = f2bf(acc[m * 8 + dt][r]);
      }
    }
  }
  // V: transposed store [b][d][t], 4 consecutive t -> 8B packed store
  {
    int t0 = mrow0 + wave * 16 + h4 * 4;
    int b = mrow0 >> 12;       // tiles never cross batch (64 | 4096)
    int tl = t0 & (NT - 1);
    #pragma unroll
    for (int dt = 0; dt < 8; ++dt) {
      int d = dt * 16 + r16;
      u16x4 pk;
      #pragma unroll
      for (int r = 0; r < 4; ++r) pk[r] = f2bf(acc[16 + dt][r]);
      *(u16x4*)(Vt + (size_t)b * (ND * NT) + (size_t)d * NT + tl) = pk;
    }
  }
}

// ---------------------------------------------------------------------------
// Kernel 3: flash attention with kv-split=2. Block = 1 wave = 16 q-rows.
// grid = (T/16, B, 2). Writes unnormalized partials Opart/Mpart/Lpart.
// ---------------------------------------------------------------------------
__global__ void attn_kernel(const unsigned short* __restrict__ Qb,
                            const unsigned short* __restrict__ Kb,
                            const unsigned short* __restrict__ Vt,
                            float* __restrict__ Opart, float* __restrict__ Mpart,
                            float* __restrict__ Lpart) {
  __shared__ unsigned short plds[16 * 72];  // P tile, row stride 72 (16B-aligned, depads banks)

  int qt = blockIdx.x;
  int b = blockIdx.y;
  int z = blockIdx.z;
  int lane = threadIdx.x;
  int r16 = lane & 15;
  int h4 = lane >> 4;
  int h8 = h4 * 8;

  int q0 = qt * 16;
  int kstart = z * KHALF;
  int kend = min(q0 + 16, (z + 1) * KHALF);  // exclusive

  const unsigned short* Qbb = Qb + (size_t)b * NT * ND;
  const unsigned short* Kbb = Kb + (size_t)b * NT * ND;
  const unsigned short* Vtb = Vt + (size_t)b * ND * NT;

  bf16x8 qf[4];
  #pragma unroll
  for (int dc = 0; dc < 4; ++dc)
    qf[dc] = *(const bf16x8*)(Qbb + (size_t)(q0 + r16) * ND + dc * 32 + h8);

  f32x4 accO[8];
  #pragma unroll
  for (int i = 0; i < 8; ++i) accO[i] = (f32x4){0.f, 0.f, 0.f, 0.f};
  float mr[4] = {-3e38f, -3e38f, -3e38f, -3e38f};
  float lr[4] = {0.f, 0.f, 0.f, 0.f};
  const float scale = 0.08838834764831845f;  // 1/sqrt(128)

  for (int kv0 = kstart; kv0 < kend; kv0 += 64) {
    // ---- S = Q K^T (16 q-rows x 64 keys) ----
    f32x4 s[4];
    #pragma unroll
    for (int kt = 0; kt < 4; ++kt) {
      s[kt] = (f32x4){0.f, 0.f, 0.f, 0.f};
      const unsigned short* krow = Kbb + (size_t)(kv0 + kt * 16 + r16) * ND;
      #pragma unroll
      for (int dc = 0; dc < 4; ++dc) {
        bf16x8 kf = *(const bf16x8*)(krow + dc * 32 + h8);
        s[kt] = __builtin_amdgcn_mfma_f32_16x16x32_bf16(qf[dc], kf, s[kt], 0, 0, 0);
      }
    }
    // ---- mask + scale, tile row-max ----
    float tmax[4] = {-3e38f, -3e38f, -3e38f, -3e38f};
    #pragma unroll
    for (int kt = 0; kt < 4; ++kt) {
      int key = kv0 + kt * 16 + r16;
      #pragma unroll
      for (int r = 0; r < 4; ++r) {
        int q = q0 + h4 * 4 + r;
        float v = (key <= q && key < kend) ? s[kt][r] * scale : -3e38f;
        s[kt][r] = v;
        tmax[r] = fmaxf(tmax[r], v);
      }
    }
    #pragma unroll
    for (int r = 0; r < 4; ++r)
      #pragma unroll
      for (int msk = 1; msk < 16; msk <<= 1)
        tmax[r] = fmaxf(tmax[r], __shfl_xor(tmax[r], msk, 64));
    // ---- online softmax update ----
    float sf[4], psum[4];
    #pragma unroll
    for (int r = 0; r < 4; ++r) {
      float mn = fmaxf(mr[r], tmax[r]);
      sf[r] = __expf(mr[r] - mn);
      mr[r] = mn;
      psum[r] = 0.f;
    }
    #pragma unroll
    for (int kt = 0; kt < 4; ++kt)
      #pragma unroll
      for (int r = 0; r < 4; ++r) {
        float p = __expf(s[kt][r] - mr[r]);  // masked (-3e38) -> 0
        s[kt][r] = p;
        psum[r] += p;
      }
    #pragma unroll
    for (int r = 0; r < 4; ++r) {
      #pragma unroll
      for (int msk = 1; msk < 16; msk <<= 1)
        psum[r] += __shfl_xor(psum[r], msk, 64);
      lr[r] = lr[r] * sf[r] + psum[r];
    }
    #pragma unroll
    for (int dt = 0; dt < 8; ++dt) {
      f32x4 o = accO[dt];
      #pragma unroll
      for (int r = 0; r < 4; ++r) o[r] *= sf[r];
      accO[dt] = o;
    }
    // ---- P -> LDS (transpose C-layout to A-frag layout) ----
    #pragma unroll
    for (int kt = 0; kt < 4; ++kt)
      #pragma unroll
      for (int r = 0; r < 4; ++r)
        plds[(h4 * 4 + r) * 72 + kt * 16 + r16] = f2bf(s[kt][r]);
    // wave-private LDS: ds ops complete in order within a wave; no barrier needed
    // ---- O += P V ----
    #pragma unroll
    for (int kc = 0; kc < 2; ++kc) {
      bf16x8 pf = *(const bf16x8*)(plds + r16 * 72 + kc * 32 + h8);
      #pragma unroll
      for (int dt = 0; dt < 8; ++dt) {
        bf16x8 vf = *(const bf16x8*)(Vtb + (size_t)(dt * 16 + r16) * NT + kv0 + kc * 32 + h8);
        accO[dt] = __builtin_amdgcn_mfma_f32_16x16x32_bf16(pf, vf, accO[dt], 0, 0, 0);
      }
    }
  }

  // ---- epilogue: write partials (empty split writes m=-3e38, l=0, O=0) ----
  size_t pbase = ((size_t)z * NBATCH + b) * NT + q0;
  #pragma unroll
  for (int dt = 0; dt < 8; ++dt)
    #pragma unroll
    for (int r = 0; r < 4; ++r)
      Opart[(pbase + h4 * 4 + r) * ND + dt * 16 + r16] = accO[dt][r];
  if (r16 == 0) {
    #pragma unroll
    for (int r = 0; r < 4; ++r) {
      Mpart[pbase + h4 * 4 + r] = mr[r];
      Lpart[pbase + h4 * 4 + r] = lr[r];
    }
  }
}

// ---------------------------------------------------------------------------
// Kernel 4: merge the 2 kv-splits -> final fp32 output
// ---------------------------------------------------------------------------
__global__ void merge_kernel(const float* __restrict__ Opart, const float* __restrict__ Mpart,
                             const float* __restrict__ Lpart, float* __restrict__ out) {
  int idx = blockIdx.x * blockDim.x + threadIdx.x;  // [0, BT*32)
  int bq = idx >> 5;
  int dv = idx & 31;
  float m0 = Mpart[bq], m1 = Mpart[BT + bq];
  float l0 = Lpart[bq], l1 = Lpart[BT + bq];
  float M = fmaxf(m0, m1);
  float e0 = __expf(m0 - M), e1 = __expf(m1 - M);
  float inv = 1.0f / (e0 * l0 + e1 * l1);
  f32x4 o0 = *(const f32x4*)(Opart + (size_t)bq * ND + dv * 4);
  f32x4 o1 = *(const f32x4*)(Opart + ((size_t)BT + bq) * ND + dv * 4);
  f32x4 o;
  #pragma unroll
  for (int i = 0; i < 4; ++i) o[i] = (e0 * o0[i] + e1 * o1[i]) * inv;
  *(f32x4*)(out + (size_t)bq * ND + dv * 4) = o;
}

// ---------------------------------------------------------------------------
extern "C" void kernel_launch(void* const* d_in, const int* in_sizes, int n_in,
                              void* d_out, int out_size, void* d_ws, size_t ws_size,
                              hipStream_t stream) {
  const float* x  = (const float*)d_in[0];
  const float* Wq = (const float*)d_in[1];
  const float* Wk = (const float*)d_in[2];
  const float* Wv = (const float*)d_in[3];

  char* ws = (char*)d_ws;
  // layout (bytes):
  //   Wt   : 3*128*1024*2      = 786432
  //   Qb   : 16384*128*2       = 4194304
  //   Kb   : 4194304
  //   Vt   : 4194304
  //   Opart: 2*16384*128*4     = 16777216
  //   Mpart: 2*16384*4         = 131072
  //   Lpart: 131072
  unsigned short* Wt = (unsigned short*)ws;
  unsigned short* Qb = (unsigned short*)(ws + 786432);
  unsigned short* Kb = (unsigned short*)(ws + 786432 + 4194304);
  unsigned short* Vt = (unsigned short*)(ws + 786432 + 2 * 4194304);
  float* Opart = (float*)(ws + 786432 + 3 * 4194304);
  float* Mpart = (float*)(ws + 786432 + 3 * 4194304 + 16777216);
  float* Lpart = (float*)(ws + 786432 + 3 * 4194304 + 16777216 + 131072);

  hipLaunchKernelGGL(wcvt_kernel, dim3(1536), dim3(256), 0, stream, Wq, Wk, Wv, Wt);
  hipLaunchKernelGGL(proj_kernel, dim3(256), dim3(256), 0, stream, x, Wt, Qb, Kb, Vt);
  hipLaunchKernelGGL(attn_kernel, dim3(NT / 16, NBATCH, 2), dim3(64), 0, stream,
                     Qb, Kb, Vt, Opart, Mpart, Lpart);
  hipLaunchKernelGGL(merge_kernel, dim3(BT * 32 / 256), dim3(256), 0, stream,
                     Opart, Mpart, Lpart, (float*)d_out);
}

// Round 3
// 259.385 us; speedup vs baseline: 1.8139x; 1.8139x over previous
//
#include <hip/hip_runtime.h>
#include <hip/hip_bf16.h>
#include <stdint.h>

// SelfAttentionHead: B=4, T=4096, C=1024, D=128, fp32 in/out.
// Pipeline: wcvt (W->bf16 transposed; Wk pre-scaled by log2e/sqrt(D)) ->
// proj (fused QKV MFMA GEMM, 8 waves/block, bf16 out, V transposed) ->
// attn (flash attention, 32 q-rows/wave, 4 waves/block, kv-split=4) -> merge.

typedef __attribute__((ext_vector_type(4))) float f32x4;
typedef __attribute__((ext_vector_type(8))) short bf16x8;
typedef __attribute__((ext_vector_type(4))) unsigned short u16x4;

#define NBATCH 4
#define NT 4096
#define NC 1024
#define ND 128
#define BT (NBATCH * NT)   // 16384
#define NSPLIT 4
#define KSPAN (NT / NSPLIT) // 1024 keys per split

// v_exp_f32 computes 2^x natively.
#define EXP2F(x) __builtin_amdgcn_exp2f(x)

__device__ __forceinline__ unsigned short f2bf(float f) {
  union { float f; uint32_t u; } v; v.f = f;
  uint32_t u = v.u;
  return (unsigned short)((u + 0x7FFFu + ((u >> 16) & 1u)) >> 16);
}

__device__ __forceinline__ bf16x8 cvt8(const f32x4 a0, const f32x4 a1) {
  bf16x8 r;
  r[0] = (short)f2bf(a0[0]); r[1] = (short)f2bf(a0[1]);
  r[2] = (short)f2bf(a0[2]); r[3] = (short)f2bf(a0[3]);
  r[4] = (short)f2bf(a1[0]); r[5] = (short)f2bf(a1[1]);
  r[6] = (short)f2bf(a1[2]); r[7] = (short)f2bf(a1[3]);
  return r;
}

// ---------------------------------------------------------------------------
// Kernel 1: Wq/Wk/Wv [C][D] fp32 -> Wt [3][D][C] bf16 (transposed).
// Wk is pre-scaled by log2(e)/sqrt(D) so attention logits come out in
// exp2 units, fully scaled.
// ---------------------------------------------------------------------------
__global__ void wcvt_kernel(const float* __restrict__ Wq, const float* __restrict__ Wk,
                            const float* __restrict__ Wv, unsigned short* __restrict__ Wt) {
  const float CK = 0.12751744f;  // log2(e)/sqrt(128)
  int idx = blockIdx.x * blockDim.x + threadIdx.x;  // [0, 3*128*1024)
  int m = idx >> 17;          // /131072
  int r = idx & 131071;
  int d = r >> 10;            // /1024
  int c = r & 1023;
  const float* W = (m == 0) ? Wq : (m == 1) ? Wk : Wv;
  float v = W[c * ND + d];
  if (m == 1) v *= CK;
  Wt[idx] = f2bf(v);
}

// ---------------------------------------------------------------------------
// Kernel 2: fused QKV projection. Block = 512 threads (8 waves), M-tile = 32.
// wave = (rowgroup rg in {0,1}) x (colgroup cg in {0..3}, 96 cols each).
// Grid = 512 blocks -> 4 waves/SIMD occupancy.
// ---------------------------------------------------------------------------
__global__ __launch_bounds__(512, 4)
void proj_kernel(const float* __restrict__ x, const unsigned short* __restrict__ Wt,
                 unsigned short* __restrict__ Qb, unsigned short* __restrict__ Kb,
                 unsigned short* __restrict__ Vt) {
  int wave = threadIdx.x >> 6;
  int lane = threadIdx.x & 63;
  int r16 = lane & 15;
  int h4 = lane >> 4;
  int h8 = h4 * 8;
  int rg = wave & 1;
  int cg = wave >> 1;

  int arow = blockIdx.x * 32 + rg * 16 + r16;
  const float* xr = x + (size_t)arow * NC;

  f32x4 acc[6];
  #pragma unroll
  for (int i = 0; i < 6; ++i) acc[i] = (f32x4){0.f, 0.f, 0.f, 0.f};

  for (int c0 = 0; c0 < NC; c0 += 32) {
    const f32x4 a0 = *(const f32x4*)(xr + c0 + h8);
    const f32x4 a1 = *(const f32x4*)(xr + c0 + h8 + 4);
    bf16x8 af = cvt8(a0, a1);
    #pragma unroll
    for (int nt = 0; nt < 6; ++nt) {
      const unsigned short* wrow =
          Wt + (size_t)(cg * 96 + nt * 16 + r16) * NC + c0 + h8;
      bf16x8 bfr = *(const bf16x8*)wrow;
      acc[nt] = __builtin_amdgcn_mfma_f32_16x16x32_bf16(af, bfr, acc[nt], 0, 0, 0);
    }
  }

  // Epilogue. C layout: col(d) = r16, row(t) = h4*4 + reg.
  int trow = blockIdx.x * 32 + rg * 16 + h4 * 4;
  #pragma unroll
  for (int nt = 0; nt < 6; ++nt) {
    int col0 = cg * 96 + nt * 16;
    int mat = col0 >> 7;
    int d = (col0 & 127) + r16;
    if (mat < 2) {
      unsigned short* dst = (mat == 0) ? Qb : Kb;
      #pragma unroll
      for (int r = 0; r < 4; ++r)
        dst[(size_t)(trow + r) * ND + d] = f2bf(acc[nt][r]);
    } else {
      int b = trow >> 12;            // 32 | 4096: tile never crosses batch
      int tl = trow & (NT - 1);
      u16x4 pk;
      #pragma unroll
      for (int r = 0; r < 4; ++r) pk[r] = f2bf(acc[nt][r]);
      *(u16x4*)(Vt + (size_t)b * (ND * NT) + (size_t)d * NT + tl) = pk;
    }
  }
}

// ---------------------------------------------------------------------------
// Kernel 3: flash attention, kv-split = 4. Block = 4 waves (256 thr), each
// wave owns 32 q-rows (2 row-fragments). Grid = (T/128, B, NSPLIT).
// Logits are already in exp2 units (Wk pre-scaled). Defer-max (T13).
// ---------------------------------------------------------------------------
__global__ __launch_bounds__(256, 2)
void attn_kernel(const unsigned short* __restrict__ Qb,
                 const unsigned short* __restrict__ Kb,
                 const unsigned short* __restrict__ Vt,
                 float* __restrict__ Opart, float* __restrict__ Mpart,
                 float* __restrict__ Lpart) {
  __shared__ unsigned short plds[4][32][72];

  int wave = threadIdx.x >> 6;
  int lane = threadIdx.x & 63;
  int r16 = lane & 15;
  int h4 = lane >> 4;
  int h8 = h4 * 8;

  int b = blockIdx.y;
  int z = blockIdx.z;
  int q0 = blockIdx.x * 128 + wave * 32;
  int kstart = z * KSPAN;
  int kend = min(q0 + 32, kstart + KSPAN);   // exclusive

  const unsigned short* Qbb = Qb + (size_t)b * NT * ND;
  const unsigned short* Kbb = Kb + (size_t)b * NT * ND;
  const unsigned short* Vtb = Vt + (size_t)b * ND * NT;

  bf16x8 qf[2][4];
  #pragma unroll
  for (int f = 0; f < 2; ++f)
    #pragma unroll
    for (int dc = 0; dc < 4; ++dc)
      qf[f][dc] = *(const bf16x8*)(Qbb + (size_t)(q0 + f * 16 + r16) * ND + dc * 32 + h8);

  f32x4 accO[2][8];
  #pragma unroll
  for (int f = 0; f < 2; ++f)
    #pragma unroll
    for (int i = 0; i < 8; ++i) accO[f][i] = (f32x4){0.f, 0.f, 0.f, 0.f};
  float mr[2][4], lr[2][4];
  #pragma unroll
  for (int f = 0; f < 2; ++f)
    #pragma unroll
    for (int r = 0; r < 4; ++r) { mr[f][r] = -3e38f; lr[f][r] = 0.f; }

  for (int kv0 = kstart; kv0 < kend; kv0 += 64) {
    // ---- S = Q K^T : 2 rowfrags x 4 keytiles, K-frag shared across rowfrags
    f32x4 s[2][4];
    __builtin_amdgcn_s_setprio(1);
    #pragma unroll
    for (int kt = 0; kt < 4; ++kt) {
      s[0][kt] = (f32x4){0.f, 0.f, 0.f, 0.f};
      s[1][kt] = (f32x4){0.f, 0.f, 0.f, 0.f};
      const unsigned short* krow = Kbb + (size_t)(kv0 + kt * 16 + r16) * ND;
      #pragma unroll
      for (int dc = 0; dc < 4; ++dc) {
        bf16x8 kf = *(const bf16x8*)(krow + dc * 32 + h8);
        s[0][kt] = __builtin_amdgcn_mfma_f32_16x16x32_bf16(qf[0][dc], kf, s[0][kt], 0, 0, 0);
        s[1][kt] = __builtin_amdgcn_mfma_f32_16x16x32_bf16(qf[1][dc], kf, s[1][kt], 0, 0, 0);
      }
    }
    __builtin_amdgcn_s_setprio(0);

    // ---- mask, tile row-max (logits already in exp2 units) ----
    float tmax[2][4];
    #pragma unroll
    for (int f = 0; f < 2; ++f)
      #pragma unroll
      for (int r = 0; r < 4; ++r) tmax[f][r] = -3e38f;
    #pragma unroll
    for (int kt = 0; kt < 4; ++kt) {
      int key = kv0 + kt * 16 + r16;
      #pragma unroll
      for (int f = 0; f < 2; ++f)
        #pragma unroll
        for (int r = 0; r < 4; ++r) {
          int q = q0 + f * 16 + h4 * 4 + r;
          float v = (key <= q && key < kend) ? s[f][kt][r] : -3e38f;
          s[f][kt][r] = v;
          tmax[f][r] = fmaxf(tmax[f][r], v);
        }
    }
    #pragma unroll
    for (int f = 0; f < 2; ++f)
      #pragma unroll
      for (int r = 0; r < 4; ++r)
        #pragma unroll
        for (int msk = 1; msk < 16; msk <<= 1)
          tmax[f][r] = fmaxf(tmax[f][r], __shfl_xor(tmax[f][r], msk, 64));

    // ---- defer-max: only rescale when max grew past threshold (exp2 units)
    bool grow = false;
    #pragma unroll
    for (int f = 0; f < 2; ++f)
      #pragma unroll
      for (int r = 0; r < 4; ++r) grow = grow || (tmax[f][r] > mr[f][r] + 11.0f);
    if (__any(grow)) {
      #pragma unroll
      for (int f = 0; f < 2; ++f) {
        float sf[4];
        #pragma unroll
        for (int r = 0; r < 4; ++r) {
          float mn = fmaxf(mr[f][r], tmax[f][r]);
          sf[r] = EXP2F(mr[f][r] - mn);
          mr[f][r] = mn;
          lr[f][r] *= sf[r];
        }
        #pragma unroll
        for (int dt = 0; dt < 8; ++dt) {
          #pragma unroll
          for (int r = 0; r < 4; ++r) accO[f][dt][r] *= sf[r];
        }
      }
    }

    // ---- P = exp2(S - m), row-sums ----
    float psum[2][4];
    #pragma unroll
    for (int f = 0; f < 2; ++f)
      #pragma unroll
      for (int r = 0; r < 4; ++r) psum[f][r] = 0.f;
    #pragma unroll
    for (int kt = 0; kt < 4; ++kt)
      #pragma unroll
      for (int f = 0; f < 2; ++f)
        #pragma unroll
        for (int r = 0; r < 4; ++r) {
          float p = EXP2F(s[f][kt][r] - mr[f][r]);  // masked -> 0
          s[f][kt][r] = p;
          psum[f][r] += p;
        }
    #pragma unroll
    for (int f = 0; f < 2; ++f)
      #pragma unroll
      for (int r = 0; r < 4; ++r) {
        #pragma unroll
        for (int msk = 1; msk < 16; msk <<= 1)
          psum[f][r] += __shfl_xor(psum[f][r], msk, 64);
        lr[f][r] += psum[f][r];
      }

    // ---- P -> LDS (C-layout -> A-frag layout), wave-private buffer ----
    #pragma unroll
    for (int kt = 0; kt < 4; ++kt)
      #pragma unroll
      for (int f = 0; f < 2; ++f)
        #pragma unroll
        for (int r = 0; r < 4; ++r)
          plds[wave][f * 16 + h4 * 4 + r][kt * 16 + r16] = f2bf(s[f][kt][r]);

    // ---- O += P V ----
    __builtin_amdgcn_s_setprio(1);
    #pragma unroll
    for (int kc = 0; kc < 2; ++kc) {
      bf16x8 pf0 = *(const bf16x8*)(&plds[wave][r16][kc * 32 + h8]);
      bf16x8 pf1 = *(const bf16x8*)(&plds[wave][16 + r16][kc * 32 + h8]);
      #pragma unroll
      for (int dt = 0; dt < 8; ++dt) {
        bf16x8 vf = *(const bf16x8*)(Vtb + (size_t)(dt * 16 + r16) * NT + kv0 + kc * 32 + h8);
        accO[0][dt] = __builtin_amdgcn_mfma_f32_16x16x32_bf16(pf0, vf, accO[0][dt], 0, 0, 0);
        accO[1][dt] = __builtin_amdgcn_mfma_f32_16x16x32_bf16(pf1, vf, accO[1][dt], 0, 0, 0);
      }
    }
    __builtin_amdgcn_s_setprio(0);
  }

  // ---- epilogue: unnormalized partials (empty range -> m=-3e38, l=0, O=0)
  size_t pbase = ((size_t)z * NBATCH + b) * NT + q0;
  #pragma unroll
  for (int f = 0; f < 2; ++f)
    #pragma unroll
    for (int dt = 0; dt < 8; ++dt)
      #pragma unroll
      for (int r = 0; r < 4; ++r)
        Opart[(pbase + f * 16 + h4 * 4 + r) * ND + dt * 16 + r16] = accO[f][dt][r];
  if (r16 == 0) {
    #pragma unroll
    for (int f = 0; f < 2; ++f)
      #pragma unroll
      for (int r = 0; r < 4; ++r) {
        Mpart[pbase + f * 16 + h4 * 4 + r] = mr[f][r];
        Lpart[pbase + f * 16 + h4 * 4 + r] = lr[f][r];
      }
  }
}

// ---------------------------------------------------------------------------
// Kernel 4: merge the 4 kv-splits -> final fp32 output (exp2 units)
// ---------------------------------------------------------------------------
__global__ void merge_kernel(const float* __restrict__ Opart, const float* __restrict__ Mpart,
                             const float* __restrict__ Lpart, float* __restrict__ out) {
  int idx = blockIdx.x * blockDim.x + threadIdx.x;  // [0, BT*32)
  int bq = idx >> 5;
  int dv = idx & 31;
  float m[NSPLIT], l[NSPLIT];
  float M = -3e38f;
  #pragma unroll
  for (int zz = 0; zz < NSPLIT; ++zz) {
    m[zz] = Mpart[(size_t)zz * BT + bq];
    l[zz] = Lpart[(size_t)zz * BT + bq];
    M = fmaxf(M, m[zz]);
  }
  float denom = 0.f;
  float e[NSPLIT];
  #pragma unroll
  for (int zz = 0; zz < NSPLIT; ++zz) {
    e[zz] = EXP2F(m[zz] - M);
    denom += e[zz] * l[zz];
  }
  float inv = 1.0f / denom;
  f32x4 o = (f32x4){0.f, 0.f, 0.f, 0.f};
  #pragma unroll
  for (int zz = 0; zz < NSPLIT; ++zz) {
    f32x4 oz = *(const f32x4*)(Opart + ((size_t)zz * BT + bq) * ND + dv * 4);
    #pragma unroll
    for (int i = 0; i < 4; ++i) o[i] += e[zz] * oz[i];
  }
  #pragma unroll
  for (int i = 0; i < 4; ++i) o[i] *= inv;
  *(f32x4*)(out + (size_t)bq * ND + dv * 4) = o;
}

// ---------------------------------------------------------------------------
extern "C" void kernel_launch(void* const* d_in, const int* in_sizes, int n_in,
                              void* d_out, int out_size, void* d_ws, size_t ws_size,
                              hipStream_t stream) {
  const float* x  = (const float*)d_in[0];
  const float* Wq = (const float*)d_in[1];
  const float* Wk = (const float*)d_in[2];
  const float* Wv = (const float*)d_in[3];

  char* ws = (char*)d_ws;
  // layout (bytes):
  //   Wt   : 3*128*1024*2          =   786432
  //   Qb   : 16384*128*2           =  4194304
  //   Kb   : 4194304
  //   Vt   : 4194304
  //   Opart: 4*16384*128*4         = 33554432
  //   Mpart: 4*16384*4             =   262144
  //   Lpart:                          262144
  unsigned short* Wt = (unsigned short*)ws;
  unsigned short* Qb = (unsigned short*)(ws + 786432);
  unsigned short* Kb = (unsigned short*)(ws + 786432 + 4194304);
  unsigned short* Vt = (unsigned short*)(ws + 786432 + 2 * 4194304);
  float* Opart = (float*)(ws + 786432 + 3 * 4194304);
  float* Mpart = (float*)(ws + 786432 + 3 * 4194304 + 33554432);
  float* Lpart = (float*)(ws + 786432 + 3 * 4194304 + 33554432 + 262144);

  hipLaunchKernelGGL(wcvt_kernel, dim3(1536), dim3(256), 0, stream, Wq, Wk, Wv, Wt);
  hipLaunchKernelGGL(proj_kernel, dim3(BT / 32), dim3(512), 0, stream, x, Wt, Qb, Kb, Vt);
  hipLaunchKernelGGL(attn_kernel, dim3(NT / 128, NBATCH, NSPLIT), dim3(256), 0, stream,
                     Qb, Kb, Vt, Opart, Mpart, Lpart);
  hipLaunchKernelGGL(merge_kernel, dim3(BT * 32 / 256), dim3(256), 0, stream,
                     Opart, Mpart, Lpart, (float*)d_out);
}

// Round 4
// 197.836 us; speedup vs baseline: 2.3782x; 1.3111x over previous
//
#include <hip/hip_runtime.h>
#include <hip/hip_bf16.h>
#include <stdint.h>

// SelfAttentionHead: B=4, T=4096, C=1024, D=128, fp32 in/out.
// wcvt -> proj (unchanged) -> attn (LDS-staged K/V, XOR-swizzle, kv-split=8,
// bf16 partials) -> merge (variable split count per row).

typedef __attribute__((ext_vector_type(4))) float f32x4;
typedef __attribute__((ext_vector_type(8))) short bf16x8;
typedef __attribute__((ext_vector_type(4))) unsigned short u16x4;

#define NBATCH 4
#define NT 4096
#define NC 1024
#define ND 128
#define BT (NBATCH * NT)   // 16384
#define NSPLIT 8
#define KSPAN (NT / NSPLIT) // 512 keys per split

#define EXP2F(x) __builtin_amdgcn_exp2f(x)

__device__ __forceinline__ unsigned short f2bf(float f) {
  union { float f; uint32_t u; } v; v.f = f;
  uint32_t u = v.u;
  return (unsigned short)((u + 0x7FFFu + ((u >> 16) & 1u)) >> 16);
}

__device__ __forceinline__ float bf2f(unsigned short h) {
  union { uint32_t u; float f; } v; v.u = ((uint32_t)h) << 16;
  return v.f;
}

__device__ __forceinline__ bf16x8 cvt8(const f32x4 a0, const f32x4 a1) {
  bf16x8 r;
  r[0] = (short)f2bf(a0[0]); r[1] = (short)f2bf(a0[1]);
  r[2] = (short)f2bf(a0[2]); r[3] = (short)f2bf(a0[3]);
  r[4] = (short)f2bf(a1[0]); r[5] = (short)f2bf(a1[1]);
  r[6] = (short)f2bf(a1[2]); r[7] = (short)f2bf(a1[3]);
  return r;
}

// async global -> LDS, 16B per lane; dest = ldsbase + lane*16 (wave-uniform base)
__device__ __forceinline__ void g2lds16(const void* g, void* l) {
  __builtin_amdgcn_global_load_lds(
      (const __attribute__((address_space(1))) unsigned int*)g,
      (__attribute__((address_space(3))) unsigned int*)l, 16, 0, 0);
}

// ---------------------------------------------------------------------------
// Kernel 1: Wq/Wk/Wv [C][D] fp32 -> Wt [3][D][C] bf16 (transposed).
// Wk pre-scaled by log2(e)/sqrt(D): logits in exp2 units.
// ---------------------------------------------------------------------------
__global__ void wcvt_kernel(const float* __restrict__ Wq, const float* __restrict__ Wk,
                            const float* __restrict__ Wv, unsigned short* __restrict__ Wt) {
  const float CK = 0.12751744f;  // log2(e)/sqrt(128)
  int idx = blockIdx.x * blockDim.x + threadIdx.x;  // [0, 3*128*1024)
  int m = idx >> 17;
  int r = idx & 131071;
  int d = r >> 10;
  int c = r & 1023;
  const float* W = (m == 0) ? Wq : (m == 1) ? Wk : Wv;
  float v = W[c * ND + d];
  if (m == 1) v *= CK;
  Wt[idx] = f2bf(v);
}

// ---------------------------------------------------------------------------
// Kernel 2: fused QKV projection (unchanged from round 3).
// ---------------------------------------------------------------------------
__global__ __launch_bounds__(512, 4)
void proj_kernel(const float* __restrict__ x, const unsigned short* __restrict__ Wt,
                 unsigned short* __restrict__ Qb, unsigned short* __restrict__ Kb,
                 unsigned short* __restrict__ Vt) {
  int wave = threadIdx.x >> 6;
  int lane = threadIdx.x & 63;
  int r16 = lane & 15;
  int h4 = lane >> 4;
  int h8 = h4 * 8;
  int rg = wave & 1;
  int cg = wave >> 1;

  int arow = blockIdx.x * 32 + rg * 16 + r16;
  const float* xr = x + (size_t)arow * NC;

  f32x4 acc[6];
  #pragma unroll
  for (int i = 0; i < 6; ++i) acc[i] = (f32x4){0.f, 0.f, 0.f, 0.f};

  for (int c0 = 0; c0 < NC; c0 += 32) {
    const f32x4 a0 = *(const f32x4*)(xr + c0 + h8);
    const f32x4 a1 = *(const f32x4*)(xr + c0 + h8 + 4);
    bf16x8 af = cvt8(a0, a1);
    #pragma unroll
    for (int nt = 0; nt < 6; ++nt) {
      const unsigned short* wrow =
          Wt + (size_t)(cg * 96 + nt * 16 + r16) * NC + c0 + h8;
      bf16x8 bfr = *(const bf16x8*)wrow;
      acc[nt] = __builtin_amdgcn_mfma_f32_16x16x32_bf16(af, bfr, acc[nt], 0, 0, 0);
    }
  }

  int trow = blockIdx.x * 32 + rg * 16 + h4 * 4;
  #pragma unroll
  for (int nt = 0; nt < 6; ++nt) {
    int col0 = cg * 96 + nt * 16;
    int mat = col0 >> 7;
    int d = (col0 & 127) + r16;
    if (mat < 2) {
      unsigned short* dst = (mat == 0) ? Qb : Kb;
      #pragma unroll
      for (int r = 0; r < 4; ++r)
        dst[(size_t)(trow + r) * ND + d] = f2bf(acc[nt][r]);
    } else {
      int b = trow >> 12;
      int tl = trow & (NT - 1);
      u16x4 pk;
      #pragma unroll
      for (int r = 0; r < 4; ++r) pk[r] = f2bf(acc[nt][r]);
      *(u16x4*)(Vt + (size_t)b * (ND * NT) + (size_t)d * NT + tl) = pk;
    }
  }
}

// ---------------------------------------------------------------------------
// Kernel 3: flash attention v2. Block = 4 waves (256 thr), wave = 32 q-rows.
// K/V tiles staged cooperatively in LDS (global_load_lds, linear dest,
// pre-swizzled source; XOR swizzle slot ^= row&7 -> conflict-free b128 reads).
// Grid = (T/128, B, NSPLIT). Partials: Opart bf16, Mpart/Lpart f32.
// ---------------------------------------------------------------------------
__global__ __launch_bounds__(256, 2)
void attn_kernel(const unsigned short* __restrict__ Qb,
                 const unsigned short* __restrict__ Kb,
                 const unsigned short* __restrict__ Vt,
                 unsigned short* __restrict__ Opart, float* __restrict__ Mpart,
                 float* __restrict__ Lpart) {
  __shared__ unsigned short kbuf[64 * 128];   // [krow][d], row stride 256B, swizzled
  __shared__ unsigned short vbuf[128 * 64];   // [d][t],   row stride 128B, swizzled
  __shared__ unsigned short plds[4][32][72];  // per-wave P transpose buffer

  int wave = threadIdx.x >> 6;
  int lane = threadIdx.x & 63;
  int r16 = lane & 15;
  int h4 = lane >> 4;
  int h8 = h4 * 8;

  int b = blockIdx.y;
  int z = blockIdx.z;
  int qb0 = blockIdx.x * 128;
  int kstart = z * KSPAN;
  int kend = min(qb0 + 128, kstart + KSPAN);  // exclusive, multiple of 64
  if (kend <= kstart) return;                 // empty block (uniform exit)

  int q0 = qb0 + wave * 32;

  const unsigned short* Qbb = Qb + (size_t)b * NT * ND;
  const unsigned short* Kbb = Kb + (size_t)b * NT * ND;
  const unsigned short* Vtb = Vt + (size_t)b * ND * NT;

  bf16x8 qf[2][4];
  #pragma unroll
  for (int f = 0; f < 2; ++f)
    #pragma unroll
    for (int dc = 0; dc < 4; ++dc)
      qf[f][dc] = *(const bf16x8*)(Qbb + (size_t)(q0 + f * 16 + r16) * ND + dc * 32 + h8);

  f32x4 accO[2][8];
  #pragma unroll
  for (int f = 0; f < 2; ++f)
    #pragma unroll
    for (int i = 0; i < 8; ++i) accO[f][i] = (f32x4){0.f, 0.f, 0.f, 0.f};
  float mr[2][4], lr[2][4];
  #pragma unroll
  for (int f = 0; f < 2; ++f)
    #pragma unroll
    for (int r = 0; r < 4; ++r) { mr[f][r] = -1e30f; lr[f][r] = 0.f; }

  for (int kv0 = kstart; kv0 < kend; kv0 += 64) {
    // ---- stage K [64][128] and V [128][64] into LDS (all 4 waves) ----
    #pragma unroll
    for (int i = 0; i < 4; ++i) {
      int e = i * 256 + wave * 64 + lane;   // chunk id 0..1023, 16B each
      int krow = e >> 4, ks = e & 15;
      const char* gk = (const char*)(Kbb + (size_t)(kv0 + krow) * ND)
                       + ((ks * 16) ^ ((krow & 7) << 4));
      g2lds16(gk, (char*)kbuf + (size_t)(i * 256 + wave * 64) * 16);
    }
    #pragma unroll
    for (int i = 0; i < 4; ++i) {
      int e = i * 256 + wave * 64 + lane;
      int vrow = e >> 3, vs = e & 7;
      const char* gv = (const char*)(Vtb + (size_t)vrow * NT + kv0)
                       + ((vs * 16) ^ ((vrow & 7) << 4));
      g2lds16(gv, (char*)vbuf + (size_t)(i * 256 + wave * 64) * 16);
    }
    __syncthreads();   // drains vmcnt (global_load_lds) + lgkmcnt

    if (kv0 < q0 + 32) {   // wave-uniform: this wave has unmasked keys
      // ---- S = Q K^T ----
      f32x4 s[2][4];
      __builtin_amdgcn_s_setprio(1);
      #pragma unroll
      for (int kt = 0; kt < 4; ++kt) {
        s[0][kt] = (f32x4){0.f, 0.f, 0.f, 0.f};
        s[1][kt] = (f32x4){0.f, 0.f, 0.f, 0.f};
        int krow = kt * 16 + r16;
        #pragma unroll
        for (int dc = 0; dc < 4; ++dc) {
          int off = krow * 256 + ((dc * 64 + h4 * 16) ^ ((krow & 7) << 4));
          bf16x8 kf = *(const bf16x8*)((const char*)kbuf + off);
          s[0][kt] = __builtin_amdgcn_mfma_f32_16x16x32_bf16(qf[0][dc], kf, s[0][kt], 0, 0, 0);
          s[1][kt] = __builtin_amdgcn_mfma_f32_16x16x32_bf16(qf[1][dc], kf, s[1][kt], 0, 0, 0);
        }
      }
      __builtin_amdgcn_s_setprio(0);

      // ---- mask + tile row-max ----
      float tmax[2][4];
      #pragma unroll
      for (int f = 0; f < 2; ++f)
        #pragma unroll
        for (int r = 0; r < 4; ++r) tmax[f][r] = -3e38f;
      #pragma unroll
      for (int kt = 0; kt < 4; ++kt) {
        int key = kv0 + kt * 16 + r16;
        #pragma unroll
        for (int f = 0; f < 2; ++f)
          #pragma unroll
          for (int r = 0; r < 4; ++r) {
            int q = q0 + f * 16 + h4 * 4 + r;
            float v = (key <= q) ? s[f][kt][r] : -3e38f;
            s[f][kt][r] = v;
            tmax[f][r] = fmaxf(tmax[f][r], v);
          }
      }
      #pragma unroll
      for (int f = 0; f < 2; ++f)
        #pragma unroll
        for (int r = 0; r < 4; ++r)
          #pragma unroll
          for (int msk = 1; msk < 16; msk <<= 1)
            tmax[f][r] = fmaxf(tmax[f][r], __shfl_xor(tmax[f][r], msk, 64));

      // ---- defer-max rescale ----
      bool grow = false;
      #pragma unroll
      for (int f = 0; f < 2; ++f)
        #pragma unroll
        for (int r = 0; r < 4; ++r) grow = grow || (tmax[f][r] > mr[f][r] + 11.0f);
      if (__any(grow)) {
        #pragma unroll
        for (int f = 0; f < 2; ++f) {
          float sf[4];
          #pragma unroll
          for (int r = 0; r < 4; ++r) {
            float mn = fmaxf(mr[f][r], tmax[f][r]);
            sf[r] = EXP2F(mr[f][r] - mn);
            mr[f][r] = mn;
            lr[f][r] *= sf[r];
          }
          #pragma unroll
          for (int dt = 0; dt < 8; ++dt) {
            #pragma unroll
            for (int r = 0; r < 4; ++r) accO[f][dt][r] *= sf[r];
          }
        }
      }

      // ---- P = exp2(S - m); per-lane partial row-sums (reduced in epilogue)
      #pragma unroll
      for (int kt = 0; kt < 4; ++kt)
        #pragma unroll
        for (int f = 0; f < 2; ++f)
          #pragma unroll
          for (int r = 0; r < 4; ++r) {
            float p = EXP2F(s[f][kt][r] - mr[f][r]);
            s[f][kt][r] = p;
            lr[f][r] += p;
          }

      // ---- P -> LDS (wave-private transpose) ----
      #pragma unroll
      for (int kt = 0; kt < 4; ++kt)
        #pragma unroll
        for (int f = 0; f < 2; ++f)
          #pragma unroll
          for (int r = 0; r < 4; ++r)
            plds[wave][f * 16 + h4 * 4 + r][kt * 16 + r16] = f2bf(s[f][kt][r]);

      // ---- O += P V ----
      __builtin_amdgcn_s_setprio(1);
      #pragma unroll
      for (int kc = 0; kc < 2; ++kc) {
        bf16x8 pf0 = *(const bf16x8*)(&plds[wave][r16][kc * 32 + h8]);
        bf16x8 pf1 = *(const bf16x8*)(&plds[wave][16 + r16][kc * 32 + h8]);
        #pragma unroll
        for (int dt = 0; dt < 8; ++dt) {
          int vrow = dt * 16 + r16;
          int off = vrow * 128 + ((kc * 64 + h4 * 16) ^ ((vrow & 7) << 4));
          bf16x8 vf = *(const bf16x8*)((const char*)vbuf + off);
          accO[0][dt] = __builtin_amdgcn_mfma_f32_16x16x32_bf16(pf0, vf, accO[0][dt], 0, 0, 0);
          accO[1][dt] = __builtin_amdgcn_mfma_f32_16x16x32_bf16(pf1, vf, accO[1][dt], 0, 0, 0);
        }
      }
      __builtin_amdgcn_s_setprio(0);
    }
    __syncthreads();   // buffers free for next stage
  }

  // ---- epilogue: reduce l across the 16 lanes of each row, write partials
  #pragma unroll
  for (int f = 0; f < 2; ++f)
    #pragma unroll
    for (int r = 0; r < 4; ++r)
      #pragma unroll
      for (int msk = 1; msk < 16; msk <<= 1)
        lr[f][r] += __shfl_xor(lr[f][r], msk, 64);

  size_t pbase = ((size_t)z * NBATCH + b) * NT + q0;
  #pragma unroll
  for (int f = 0; f < 2; ++f)
    #pragma unroll
    for (int dt = 0; dt < 8; ++dt)
      #pragma unroll
      for (int r = 0; r < 4; ++r)
        Opart[(pbase + f * 16 + h4 * 4 + r) * ND + dt * 16 + r16] = f2bf(accO[f][dt][r]);
  if (r16 == 0) {
    #pragma unroll
    for (int f = 0; f < 2; ++f)
      #pragma unroll
      for (int r = 0; r < 4; ++r) {
        Mpart[pbase + f * 16 + h4 * 4 + r] = mr[f][r];
        Lpart[pbase + f * 16 + h4 * 4 + r] = lr[f][r];
      }
  }
}

// ---------------------------------------------------------------------------
// Kernel 4: merge valid splits (z <= q/KSPAN) -> final fp32 output
// ---------------------------------------------------------------------------
__global__ void merge_kernel(const unsigned short* __restrict__ Opart,
                             const float* __restrict__ Mpart,
                             const float* __restrict__ Lpart, float* __restrict__ out) {
  int idx = blockIdx.x * blockDim.x + threadIdx.x;  // [0, BT*16)
  int bq = idx >> 4;
  int dg = idx & 15;      // 8 d-elements each
  int q = bq & (NT - 1);
  int nz = (q >> 9) + 1;  // q/KSPAN + 1 valid splits

  float M = -3e38f;
  #pragma unroll
  for (int zz = 0; zz < NSPLIT; ++zz)
    if (zz < nz) M = fmaxf(M, Mpart[(size_t)zz * BT + bq]);

  float denom = 0.f;
  float o[8] = {0.f, 0.f, 0.f, 0.f, 0.f, 0.f, 0.f, 0.f};
  #pragma unroll
  for (int zz = 0; zz < NSPLIT; ++zz) {
    if (zz < nz) {
      float e = EXP2F(Mpart[(size_t)zz * BT + bq] - M);
      denom += e * Lpart[(size_t)zz * BT + bq];
      bf16x8 ov = *(const bf16x8*)(Opart + ((size_t)zz * BT + bq) * ND + dg * 8);
      #pragma unroll
      for (int j = 0; j < 8; ++j) o[j] += e * bf2f((unsigned short)ov[j]);
    }
  }
  float inv = 1.0f / denom;
  f32x4 o0, o1;
  #pragma unroll
  for (int j = 0; j < 4; ++j) { o0[j] = o[j] * inv; o1[j] = o[4 + j] * inv; }
  float* dst = out + (size_t)bq * ND + dg * 8;
  *(f32x4*)dst = o0;
  *(f32x4*)(dst + 4) = o1;
}

// ---------------------------------------------------------------------------
extern "C" void kernel_launch(void* const* d_in, const int* in_sizes, int n_in,
                              void* d_out, int out_size, void* d_ws, size_t ws_size,
                              hipStream_t stream) {
  const float* x  = (const float*)d_in[0];
  const float* Wq = (const float*)d_in[1];
  const float* Wk = (const float*)d_in[2];
  const float* Wv = (const float*)d_in[3];

  char* ws = (char*)d_ws;
  // layout (bytes), total 47185920 (< proven 47448064 watermark):
  //   Qb    @ 0        : 4194304
  //   Kb    @ 4194304  : 4194304
  //   Vt    @ 8388608  : 4194304
  //   Opart @ 12582912 : 8*16384*128*2 = 33554432   (bf16)
  //   Mpart @ 46137344 : 524288
  //   Lpart @ 46661632 : 524288
  //   Wt    @ 12582912 : 786432  (ALIASES Opart: Wt dead before attn writes)
  unsigned short* Qb = (unsigned short*)ws;
  unsigned short* Kb = (unsigned short*)(ws + 4194304);
  unsigned short* Vt = (unsigned short*)(ws + 8388608);
  unsigned short* Opart = (unsigned short*)(ws + 12582912);
  float* Mpart = (float*)(ws + 46137344);
  float* Lpart = (float*)(ws + 46661632);
  unsigned short* Wt = (unsigned short*)(ws + 12582912);

  hipLaunchKernelGGL(wcvt_kernel, dim3(1536), dim3(256), 0, stream, Wq, Wk, Wv, Wt);
  hipLaunchKernelGGL(proj_kernel, dim3(BT / 32), dim3(512), 0, stream, x, Wt, Qb, Kb, Vt);
  hipLaunchKernelGGL(attn_kernel, dim3(NT / 128, NBATCH, NSPLIT), dim3(256), 0, stream,
                     Qb, Kb, Vt, Opart, Mpart, Lpart);
  hipLaunchKernelGGL(merge_kernel, dim3(BT * 16 / 256), dim3(256), 0, stream,
                     Opart, Mpart, Lpart, (float*)d_out);
}

// Round 5
// 106.628 us; speedup vs baseline: 4.4125x; 1.8554x over previous
//
#include <hip/hip_runtime.h>
#include <hip/hip_bf16.h>
#include <stdint.h>

// SelfAttentionHead: B=4, T=4096, C=1024, D=128, fp32 in/out.
// wcvt -> proj (LDS-staged 2-phase GEMM, fp32-x direct staging) ->
// attn (LDS-staged K/V, XOR-swizzle, kv-split=8, bf16 partials) -> merge.

typedef __attribute__((ext_vector_type(4))) float f32x4;
typedef __attribute__((ext_vector_type(8))) short bf16x8;
typedef __attribute__((ext_vector_type(4))) unsigned short u16x4;

#define NBATCH 4
#define NT 4096
#define NC 1024
#define ND 128
#define BT (NBATCH * NT)   // 16384
#define NSPLIT 8
#define KSPAN (NT / NSPLIT) // 512 keys per split

#define EXP2F(x) __builtin_amdgcn_exp2f(x)

__device__ __forceinline__ unsigned short f2bf(float f) {
  union { float f; uint32_t u; } v; v.f = f;
  uint32_t u = v.u;
  return (unsigned short)((u + 0x7FFFu + ((u >> 16) & 1u)) >> 16);
}

__device__ __forceinline__ float bf2f(unsigned short h) {
  union { uint32_t u; float f; } v; v.u = ((uint32_t)h) << 16;
  return v.f;
}

__device__ __forceinline__ bf16x8 cvt8(const f32x4 a0, const f32x4 a1) {
  bf16x8 r;
  r[0] = (short)f2bf(a0[0]); r[1] = (short)f2bf(a0[1]);
  r[2] = (short)f2bf(a0[2]); r[3] = (short)f2bf(a0[3]);
  r[4] = (short)f2bf(a1[0]); r[5] = (short)f2bf(a1[1]);
  r[6] = (short)f2bf(a1[2]); r[7] = (short)f2bf(a1[3]);
  return r;
}

// async global -> LDS, 16B per lane; dest = wave-uniform LDS base (+lane*16 HW)
__device__ __forceinline__ void g2lds16(const void* g, void* l) {
  __builtin_amdgcn_global_load_lds(
      (const __attribute__((address_space(1))) unsigned int*)g,
      (__attribute__((address_space(3))) unsigned int*)l, 16, 0, 0);
}

// ---------------------------------------------------------------------------
// Kernel 1: Wq/Wk/Wv [C][D] fp32 -> Wt [3][D][C] bf16 (transposed).
// Wk pre-scaled by log2(e)/sqrt(D): logits in exp2 units.
// ---------------------------------------------------------------------------
__global__ void wcvt_kernel(const float* __restrict__ Wq, const float* __restrict__ Wk,
                            const float* __restrict__ Wv, unsigned short* __restrict__ Wt) {
  const float CK = 0.12751744f;  // log2(e)/sqrt(128)
  int idx = blockIdx.x * blockDim.x + threadIdx.x;  // [0, 3*128*1024)
  int m = idx >> 17;
  int r = idx & 131071;
  int d = r >> 10;
  int c = r & 1023;
  const float* W = (m == 0) ? Wq : (m == 1) ? Wk : Wv;
  float v = W[c * ND + d];
  if (m == 1) v *= CK;
  Wt[idx] = f2bf(v);
}

// ---------------------------------------------------------------------------
// Kernel 2: fused QKV projection, v2: 2-phase LDS-staged GEMM.
// M=16384, N=384 (=3 matrices x 128), K=1024. BM=64, BN=128, BK=32.
// Grid = 256 m-tiles x 3 n-tiles = 768 blocks; 4 waves (2m x 2n), each 32x64.
// A (x, fp32) staged direct via global_load_lds with XOR slot swizzle
// (8 slots/row), converted bf16 at frag build. B (Wt, bf16) staged swizzled
// (4 slots/row). Double-buffered, prefetch-before-compute, 1 barrier/iter.
// ---------------------------------------------------------------------------
__global__ __launch_bounds__(256, 3)
void proj_kernel(const float* __restrict__ x, const unsigned short* __restrict__ Wt,
                 unsigned short* __restrict__ Qb, unsigned short* __restrict__ Kb,
                 unsigned short* __restrict__ Vt) {
  // per buffer: A 64*32*4 = 8192 B, then B 128*32*2 = 8192 B
  __shared__ char smem[2][16384];

  int w = threadIdx.x >> 6;
  int lane = threadIdx.x & 63;
  int r16 = lane & 15;
  int h4 = lane >> 4;
  int wm = w & 1;
  int wn = w >> 1;

  int mt = blockIdx.x & 255;
  int nt = blockIdx.x >> 8;      // 0:Q 1:K 2:V

  const char* xg = (const char*)(x + (size_t)(mt * 64) * NC);          // A tile base
  const char* wg = (const char*)(Wt + (size_t)(nt * 128) * NC);        // B tile base

  f32x4 acc[2][4];
  #pragma unroll
  for (int m = 0; m < 2; ++m)
    #pragma unroll
    for (int n = 0; n < 4; ++n) acc[m][n] = (f32x4){0.f, 0.f, 0.f, 0.f};

  // staging chunk ids (16B chunks): A has 512, B has 512; 4 issues/wave total
  int cA0 = (w * 2 + 0) * 64 + lane;
  int cA1 = (w * 2 + 1) * 64 + lane;

  #define STAGE(buf, t)                                                          \
    {                                                                            \
      int c0 = (t) * 32;                                                         \
      {                                                                          \
        int c = cA0, row = c >> 3, s = c & 7;                                    \
        g2lds16(xg + (size_t)row * 4096 + c0 * 4 + ((s ^ (row & 7)) << 4),       \
                smem[buf] + (w * 2 + 0) * 1024);                                 \
      }                                                                          \
      {                                                                          \
        int c = cA1, row = c >> 3, s = c & 7;                                    \
        g2lds16(xg + (size_t)row * 4096 + c0 * 4 + ((s ^ (row & 7)) << 4),       \
                smem[buf] + (w * 2 + 1) * 1024);                                 \
      }                                                                          \
      {                                                                          \
        int c = cA0, row = c >> 2, s = c & 3;                                    \
        g2lds16(wg + (size_t)row * 2048 + c0 * 2 + ((s ^ (row & 3)) << 4),       \
                smem[buf] + 8192 + (w * 2 + 0) * 1024);                          \
      }                                                                          \
      {                                                                          \
        int c = cA1, row = c >> 2, s = c & 3;                                    \
        g2lds16(wg + (size_t)row * 2048 + c0 * 2 + ((s ^ (row & 3)) << 4),       \
                smem[buf] + 8192 + (w * 2 + 1) * 1024);                          \
      }                                                                          \
    }

  STAGE(0, 0);
  __syncthreads();

  for (int t = 0; t < 32; ++t) {
    int cur = t & 1;
    if (t + 1 < 32) STAGE(cur ^ 1, t + 1);

    // A fragments (fp32 in LDS -> bf16)
    bf16x8 af[2];
    #pragma unroll
    for (int m = 0; m < 2; ++m) {
      int row = wm * 32 + m * 16 + r16;
      f32x4 a0 = *(const f32x4*)(smem[cur] + row * 128 + (((h4 * 2) ^ (row & 7)) << 4));
      f32x4 a1 = *(const f32x4*)(smem[cur] + row * 128 + (((h4 * 2 + 1) ^ (row & 7)) << 4));
      af[m] = cvt8(a0, a1);
    }
    // B fragments + MFMA
    __builtin_amdgcn_s_setprio(1);
    #pragma unroll
    for (int n = 0; n < 4; ++n) {
      int brow = wn * 64 + n * 16 + r16;
      bf16x8 bfr = *(const bf16x8*)(smem[cur] + 8192 + brow * 64 + ((h4 ^ (brow & 3)) << 4));
      acc[0][n] = __builtin_amdgcn_mfma_f32_16x16x32_bf16(af[0], bfr, acc[0][n], 0, 0, 0);
      acc[1][n] = __builtin_amdgcn_mfma_f32_16x16x32_bf16(af[1], bfr, acc[1][n], 0, 0, 0);
    }
    __builtin_amdgcn_s_setprio(0);
    __syncthreads();
  }
  #undef STAGE

  // Epilogue. acc C layout: col = r16 (within n-frag), row = h4*4 + reg.
  if (nt < 2) {
    unsigned short* dst = (nt == 0) ? Qb : Kb;
    #pragma unroll
    for (int m = 0; m < 2; ++m) {
      int t0 = mt * 64 + wm * 32 + m * 16 + h4 * 4;
      #pragma unroll
      for (int n = 0; n < 4; ++n) {
        int d = wn * 64 + n * 16 + r16;
        #pragma unroll
        for (int r = 0; r < 4; ++r)
          dst[(size_t)(t0 + r) * ND + d] = f2bf(acc[m][n][r]);
      }
    }
  } else {
    #pragma unroll
    for (int m = 0; m < 2; ++m) {
      int t0 = mt * 64 + wm * 32 + m * 16 + h4 * 4;
      int b = t0 >> 12;           // 64 | 4096: tile never crosses batch
      int tl = t0 & (NT - 1);
      #pragma unroll
      for (int n = 0; n < 4; ++n) {
        int d = wn * 64 + n * 16 + r16;
        u16x4 pk;
        #pragma unroll
        for (int r = 0; r < 4; ++r) pk[r] = f2bf(acc[m][n][r]);
        *(u16x4*)(Vt + (size_t)b * (ND * NT) + (size_t)d * NT + tl) = pk;
      }
    }
  }
}

// ---------------------------------------------------------------------------
// Kernel 3: flash attention (unchanged from round 4). Block = 4 waves,
// wave = 32 q-rows, K/V LDS-staged with XOR swizzle, kv-split = 8.
// ---------------------------------------------------------------------------
__global__ __launch_bounds__(256, 2)
void attn_kernel(const unsigned short* __restrict__ Qb,
                 const unsigned short* __restrict__ Kb,
                 const unsigned short* __restrict__ Vt,
                 unsigned short* __restrict__ Opart, float* __restrict__ Mpart,
                 float* __restrict__ Lpart) {
  __shared__ unsigned short kbuf[64 * 128];   // [krow][d], swizzled
  __shared__ unsigned short vbuf[128 * 64];   // [d][t],   swizzled
  __shared__ unsigned short plds[4][32][72];  // per-wave P transpose buffer

  int wave = threadIdx.x >> 6;
  int lane = threadIdx.x & 63;
  int r16 = lane & 15;
  int h4 = lane >> 4;
  int h8 = h4 * 8;

  int b = blockIdx.y;
  int z = blockIdx.z;
  int qb0 = blockIdx.x * 128;
  int kstart = z * KSPAN;
  int kend = min(qb0 + 128, kstart + KSPAN);
  if (kend <= kstart) return;

  int q0 = qb0 + wave * 32;

  const unsigned short* Qbb = Qb + (size_t)b * NT * ND;
  const unsigned short* Kbb = Kb + (size_t)b * NT * ND;
  const unsigned short* Vtb = Vt + (size_t)b * ND * NT;

  bf16x8 qf[2][4];
  #pragma unroll
  for (int f = 0; f < 2; ++f)
    #pragma unroll
    for (int dc = 0; dc < 4; ++dc)
      qf[f][dc] = *(const bf16x8*)(Qbb + (size_t)(q0 + f * 16 + r16) * ND + dc * 32 + h8);

  f32x4 accO[2][8];
  #pragma unroll
  for (int f = 0; f < 2; ++f)
    #pragma unroll
    for (int i = 0; i < 8; ++i) accO[f][i] = (f32x4){0.f, 0.f, 0.f, 0.f};
  float mr[2][4], lr[2][4];
  #pragma unroll
  for (int f = 0; f < 2; ++f)
    #pragma unroll
    for (int r = 0; r < 4; ++r) { mr[f][r] = -1e30f; lr[f][r] = 0.f; }

  for (int kv0 = kstart; kv0 < kend; kv0 += 64) {
    #pragma unroll
    for (int i = 0; i < 4; ++i) {
      int e = i * 256 + wave * 64 + lane;
      int krow = e >> 4, ks = e & 15;
      const char* gk = (const char*)(Kbb + (size_t)(kv0 + krow) * ND)
                       + ((ks * 16) ^ ((krow & 7) << 4));
      g2lds16(gk, (char*)kbuf + (size_t)(i * 256 + wave * 64) * 16);
    }
    #pragma unroll
    for (int i = 0; i < 4; ++i) {
      int e = i * 256 + wave * 64 + lane;
      int vrow = e >> 3, vs = e & 7;
      const char* gv = (const char*)(Vtb + (size_t)vrow * NT + kv0)
                       + ((vs * 16) ^ ((vrow & 7) << 4));
      g2lds16(gv, (char*)vbuf + (size_t)(i * 256 + wave * 64) * 16);
    }
    __syncthreads();

    if (kv0 < q0 + 32) {
      f32x4 s[2][4];
      __builtin_amdgcn_s_setprio(1);
      #pragma unroll
      for (int kt = 0; kt < 4; ++kt) {
        s[0][kt] = (f32x4){0.f, 0.f, 0.f, 0.f};
        s[1][kt] = (f32x4){0.f, 0.f, 0.f, 0.f};
        int krow = kt * 16 + r16;
        #pragma unroll
        for (int dc = 0; dc < 4; ++dc) {
          int off = krow * 256 + ((dc * 64 + h4 * 16) ^ ((krow & 7) << 4));
          bf16x8 kf = *(const bf16x8*)((const char*)kbuf + off);
          s[0][kt] = __builtin_amdgcn_mfma_f32_16x16x32_bf16(qf[0][dc], kf, s[0][kt], 0, 0, 0);
          s[1][kt] = __builtin_amdgcn_mfma_f32_16x16x32_bf16(qf[1][dc], kf, s[1][kt], 0, 0, 0);
        }
      }
      __builtin_amdgcn_s_setprio(0);

      float tmax[2][4];
      #pragma unroll
      for (int f = 0; f < 2; ++f)
        #pragma unroll
        for (int r = 0; r < 4; ++r) tmax[f][r] = -3e38f;
      #pragma unroll
      for (int kt = 0; kt < 4; ++kt) {
        int key = kv0 + kt * 16 + r16;
        #pragma unroll
        for (int f = 0; f < 2; ++f)
          #pragma unroll
          for (int r = 0; r < 4; ++r) {
            int q = q0 + f * 16 + h4 * 4 + r;
            float v = (key <= q) ? s[f][kt][r] : -3e38f;
            s[f][kt][r] = v;
            tmax[f][r] = fmaxf(tmax[f][r], v);
          }
      }
      #pragma unroll
      for (int f = 0; f < 2; ++f)
        #pragma unroll
        for (int r = 0; r < 4; ++r)
          #pragma unroll
          for (int msk = 1; msk < 16; msk <<= 1)
            tmax[f][r] = fmaxf(tmax[f][r], __shfl_xor(tmax[f][r], msk, 64));

      bool grow = false;
      #pragma unroll
      for (int f = 0; f < 2; ++f)
        #pragma unroll
        for (int r = 0; r < 4; ++r) grow = grow || (tmax[f][r] > mr[f][r] + 11.0f);
      if (__any(grow)) {
        #pragma unroll
        for (int f = 0; f < 2; ++f) {
          float sf[4];
          #pragma unroll
          for (int r = 0; r < 4; ++r) {
            float mn = fmaxf(mr[f][r], tmax[f][r]);
            sf[r] = EXP2F(mr[f][r] - mn);
            mr[f][r] = mn;
            lr[f][r] *= sf[r];
          }
          #pragma unroll
          for (int dt = 0; dt < 8; ++dt) {
            #pragma unroll
            for (int r = 0; r < 4; ++r) accO[f][dt][r] *= sf[r];
          }
        }
      }

      #pragma unroll
      for (int kt = 0; kt < 4; ++kt)
        #pragma unroll
        for (int f = 0; f < 2; ++f)
          #pragma unroll
          for (int r = 0; r < 4; ++r) {
            float p = EXP2F(s[f][kt][r] - mr[f][r]);
            s[f][kt][r] = p;
            lr[f][r] += p;
          }

      #pragma unroll
      for (int kt = 0; kt < 4; ++kt)
        #pragma unroll
        for (int f = 0; f < 2; ++f)
          #pragma unroll
          for (int r = 0; r < 4; ++r)
            plds[wave][f * 16 + h4 * 4 + r][kt * 16 + r16] = f2bf(s[f][kt][r]);

      __builtin_amdgcn_s_setprio(1);
      #pragma unroll
      for (int kc = 0; kc < 2; ++kc) {
        bf16x8 pf0 = *(const bf16x8*)(&plds[wave][r16][kc * 32 + h8]);
        bf16x8 pf1 = *(const bf16x8*)(&plds[wave][16 + r16][kc * 32 + h8]);
        #pragma unroll
        for (int dt = 0; dt < 8; ++dt) {
          int vrow = dt * 16 + r16;
          int off = vrow * 128 + ((kc * 64 + h4 * 16) ^ ((vrow & 7) << 4));
          bf16x8 vf = *(const bf16x8*)((const char*)vbuf + off);
          accO[0][dt] = __builtin_amdgcn_mfma_f32_16x16x32_bf16(pf0, vf, accO[0][dt], 0, 0, 0);
          accO[1][dt] = __builtin_amdgcn_mfma_f32_16x16x32_bf16(pf1, vf, accO[1][dt], 0, 0, 0);
        }
      }
      __builtin_amdgcn_s_setprio(0);
    }
    __syncthreads();
  }

  #pragma unroll
  for (int f = 0; f < 2; ++f)
    #pragma unroll
    for (int r = 0; r < 4; ++r)
      #pragma unroll
      for (int msk = 1; msk < 16; msk <<= 1)
        lr[f][r] += __shfl_xor(lr[f][r], msk, 64);

  size_t pbase = ((size_t)z * NBATCH + b) * NT + q0;
  #pragma unroll
  for (int f = 0; f < 2; ++f)
    #pragma unroll
    for (int dt = 0; dt < 8; ++dt)
      #pragma unroll
      for (int r = 0; r < 4; ++r)
        Opart[(pbase + f * 16 + h4 * 4 + r) * ND + dt * 16 + r16] = f2bf(accO[f][dt][r]);
  if (r16 == 0) {
    #pragma unroll
    for (int f = 0; f < 2; ++f)
      #pragma unroll
      for (int r = 0; r < 4; ++r) {
        Mpart[pbase + f * 16 + h4 * 4 + r] = mr[f][r];
        Lpart[pbase + f * 16 + h4 * 4 + r] = lr[f][r];
      }
  }
}

// ---------------------------------------------------------------------------
// Kernel 4: merge valid splits (z <= q/KSPAN) -> final fp32 output
// ---------------------------------------------------------------------------
__global__ void merge_kernel(const unsigned short* __restrict__ Opart,
                             const float* __restrict__ Mpart,
                             const float* __restrict__ Lpart, float* __restrict__ out) {
  int idx = blockIdx.x * blockDim.x + threadIdx.x;  // [0, BT*16)
  int bq = idx >> 4;
  int dg = idx & 15;
  int q = bq & (NT - 1);
  int nz = (q >> 9) + 1;

  float M = -3e38f;
  #pragma unroll
  for (int zz = 0; zz < NSPLIT; ++zz)
    if (zz < nz) M = fmaxf(M, Mpart[(size_t)zz * BT + bq]);

  float denom = 0.f;
  float o[8] = {0.f, 0.f, 0.f, 0.f, 0.f, 0.f, 0.f, 0.f};
  #pragma unroll
  for (int zz = 0; zz < NSPLIT; ++zz) {
    if (zz < nz) {
      float e = EXP2F(Mpart[(size_t)zz * BT + bq] - M);
      denom += e * Lpart[(size_t)zz * BT + bq];
      bf16x8 ov = *(const bf16x8*)(Opart + ((size_t)zz * BT + bq) * ND + dg * 8);
      #pragma unroll
      for (int j = 0; j < 8; ++j) o[j] += e * bf2f((unsigned short)ov[j]);
    }
  }
  float inv = 1.0f / denom;
  f32x4 o0, o1;
  #pragma unroll
  for (int j = 0; j < 4; ++j) { o0[j] = o[j] * inv; o1[j] = o[4 + j] * inv; }
  float* dst = out + (size_t)bq * ND + dg * 8;
  *(f32x4*)dst = o0;
  *(f32x4*)(dst + 4) = o1;
}

// ---------------------------------------------------------------------------
extern "C" void kernel_launch(void* const* d_in, const int* in_sizes, int n_in,
                              void* d_out, int out_size, void* d_ws, size_t ws_size,
                              hipStream_t stream) {
  const float* x  = (const float*)d_in[0];
  const float* Wq = (const float*)d_in[1];
  const float* Wk = (const float*)d_in[2];
  const float* Wv = (const float*)d_in[3];

  char* ws = (char*)d_ws;
  // layout (bytes), total 47185920:
  //   Qb    @ 0        : 4194304
  //   Kb    @ 4194304  : 4194304
  //   Vt    @ 8388608  : 4194304
  //   Opart @ 12582912 : 33554432 (bf16)
  //   Mpart @ 46137344 : 524288
  //   Lpart @ 46661632 : 524288
  //   Wt    @ 12582912 : 786432  (ALIASES Opart: Wt dead before attn writes)
  unsigned short* Qb = (unsigned short*)ws;
  unsigned short* Kb = (unsigned short*)(ws + 4194304);
  unsigned short* Vt = (unsigned short*)(ws + 8388608);
  unsigned short* Opart = (unsigned short*)(ws + 12582912);
  float* Mpart = (float*)(ws + 46137344);
  float* Lpart = (float*)(ws + 46661632);
  unsigned short* Wt = (unsigned short*)(ws + 12582912);

  hipLaunchKernelGGL(wcvt_kernel, dim3(1536), dim3(256), 0, stream, Wq, Wk, Wv, Wt);
  hipLaunchKernelGGL(proj_kernel, dim3(768), dim3(256), 0, stream, x, Wt, Qb, Kb, Vt);
  hipLaunchKernelGGL(attn_kernel, dim3(NT / 128, NBATCH, NSPLIT), dim3(256), 0, stream,
                     Qb, Kb, Vt, Opart, Mpart, Lpart);
  hipLaunchKernelGGL(merge_kernel, dim3(BT * 16 / 256), dim3(256), 0, stream,
                     Opart, Mpart, Lpart, (float*)d_out);
}

// Round 6
// 105.477 us; speedup vs baseline: 4.4607x; 1.0109x over previous
//
#include <hip/hip_runtime.h>
#include <hip/hip_bf16.h>
#include <stdint.h>

// SelfAttentionHead: B=4, T=4096, C=1024, D=128, fp32 in/out.
// wcvt -> proj (LDS-staged 2-phase GEMM) ->
// attn (double-buffered LDS K/V prefetch, XOR-swizzle, kv-split=8, bf16
// partials) -> merge.

typedef __attribute__((ext_vector_type(4))) float f32x4;
typedef __attribute__((ext_vector_type(8))) short bf16x8;
typedef __attribute__((ext_vector_type(4))) unsigned short u16x4;

#define NBATCH 4
#define NT 4096
#define NC 1024
#define ND 128
#define BT (NBATCH * NT)   // 16384
#define NSPLIT 8
#define KSPAN (NT / NSPLIT) // 512 keys per split

#define EXP2F(x) __builtin_amdgcn_exp2f(x)

__device__ __forceinline__ unsigned short f2bf(float f) {
  union { float f; uint32_t u; } v; v.f = f;
  uint32_t u = v.u;
  return (unsigned short)((u + 0x7FFFu + ((u >> 16) & 1u)) >> 16);
}

__device__ __forceinline__ float bf2f(unsigned short h) {
  union { uint32_t u; float f; } v; v.u = ((uint32_t)h) << 16;
  return v.f;
}

__device__ __forceinline__ bf16x8 cvt8(const f32x4 a0, const f32x4 a1) {
  bf16x8 r;
  r[0] = (short)f2bf(a0[0]); r[1] = (short)f2bf(a0[1]);
  r[2] = (short)f2bf(a0[2]); r[3] = (short)f2bf(a0[3]);
  r[4] = (short)f2bf(a1[0]); r[5] = (short)f2bf(a1[1]);
  r[6] = (short)f2bf(a1[2]); r[7] = (short)f2bf(a1[3]);
  return r;
}

// async global -> LDS, 16B per lane; dest = wave-uniform LDS base (+lane*16 HW)
__device__ __forceinline__ void g2lds16(const void* g, void* l) {
  __builtin_amdgcn_global_load_lds(
      (const __attribute__((address_space(1))) unsigned int*)g,
      (__attribute__((address_space(3))) unsigned int*)l, 16, 0, 0);
}

// ---------------------------------------------------------------------------
// Kernel 1: Wq/Wk/Wv [C][D] fp32 -> Wt [3][D][C] bf16 (transposed).
// Wk pre-scaled by log2(e)/sqrt(D): logits in exp2 units.
// ---------------------------------------------------------------------------
__global__ void wcvt_kernel(const float* __restrict__ Wq, const float* __restrict__ Wk,
                            const float* __restrict__ Wv, unsigned short* __restrict__ Wt) {
  const float CK = 0.12751744f;  // log2(e)/sqrt(128)
  int idx = blockIdx.x * blockDim.x + threadIdx.x;  // [0, 3*128*1024)
  int m = idx >> 17;
  int r = idx & 131071;
  int d = r >> 10;
  int c = r & 1023;
  const float* W = (m == 0) ? Wq : (m == 1) ? Wk : Wv;
  float v = W[c * ND + d];
  if (m == 1) v *= CK;
  Wt[idx] = f2bf(v);
}

// ---------------------------------------------------------------------------
// Kernel 2: fused QKV projection (unchanged from round 5).
// ---------------------------------------------------------------------------
__global__ __launch_bounds__(256, 3)
void proj_kernel(const float* __restrict__ x, const unsigned short* __restrict__ Wt,
                 unsigned short* __restrict__ Qb, unsigned short* __restrict__ Kb,
                 unsigned short* __restrict__ Vt) {
  __shared__ char smem[2][16384];

  int w = threadIdx.x >> 6;
  int lane = threadIdx.x & 63;
  int r16 = lane & 15;
  int h4 = lane >> 4;
  int wm = w & 1;
  int wn = w >> 1;

  int mt = blockIdx.x & 255;
  int nt = blockIdx.x >> 8;      // 0:Q 1:K 2:V

  const char* xg = (const char*)(x + (size_t)(mt * 64) * NC);
  const char* wg = (const char*)(Wt + (size_t)(nt * 128) * NC);

  f32x4 acc[2][4];
  #pragma unroll
  for (int m = 0; m < 2; ++m)
    #pragma unroll
    for (int n = 0; n < 4; ++n) acc[m][n] = (f32x4){0.f, 0.f, 0.f, 0.f};

  int cA0 = (w * 2 + 0) * 64 + lane;
  int cA1 = (w * 2 + 1) * 64 + lane;

  #define STAGE(buf, t)                                                          \
    {                                                                            \
      int c0 = (t) * 32;                                                         \
      {                                                                          \
        int c = cA0, row = c >> 3, s = c & 7;                                    \
        g2lds16(xg + (size_t)row * 4096 + c0 * 4 + ((s ^ (row & 7)) << 4),       \
                smem[buf] + (w * 2 + 0) * 1024);                                 \
      }                                                                          \
      {                                                                          \
        int c = cA1, row = c >> 3, s = c & 7;                                    \
        g2lds16(xg + (size_t)row * 4096 + c0 * 4 + ((s ^ (row & 7)) << 4),       \
                smem[buf] + (w * 2 + 1) * 1024);                                 \
      }                                                                          \
      {                                                                          \
        int c = cA0, row = c >> 2, s = c & 3;                                    \
        g2lds16(wg + (size_t)row * 2048 + c0 * 2 + ((s ^ (row & 3)) << 4),       \
                smem[buf] + 8192 + (w * 2 + 0) * 1024);                          \
      }                                                                          \
      {                                                                          \
        int c = cA1, row = c >> 2, s = c & 3;                                    \
        g2lds16(wg + (size_t)row * 2048 + c0 * 2 + ((s ^ (row & 3)) << 4),       \
                smem[buf] + 8192 + (w * 2 + 1) * 1024);                          \
      }                                                                          \
    }

  STAGE(0, 0);
  __syncthreads();

  for (int t = 0; t < 32; ++t) {
    int cur = t & 1;
    if (t + 1 < 32) STAGE(cur ^ 1, t + 1);

    bf16x8 af[2];
    #pragma unroll
    for (int m = 0; m < 2; ++m) {
      int row = wm * 32 + m * 16 + r16;
      f32x4 a0 = *(const f32x4*)(smem[cur] + row * 128 + (((h4 * 2) ^ (row & 7)) << 4));
      f32x4 a1 = *(const f32x4*)(smem[cur] + row * 128 + (((h4 * 2 + 1) ^ (row & 7)) << 4));
      af[m] = cvt8(a0, a1);
    }
    __builtin_amdgcn_s_setprio(1);
    #pragma unroll
    for (int n = 0; n < 4; ++n) {
      int brow = wn * 64 + n * 16 + r16;
      bf16x8 bfr = *(const bf16x8*)(smem[cur] + 8192 + brow * 64 + ((h4 ^ (brow & 3)) << 4));
      acc[0][n] = __builtin_amdgcn_mfma_f32_16x16x32_bf16(af[0], bfr, acc[0][n], 0, 0, 0);
      acc[1][n] = __builtin_amdgcn_mfma_f32_16x16x32_bf16(af[1], bfr, acc[1][n], 0, 0, 0);
    }
    __builtin_amdgcn_s_setprio(0);
    __syncthreads();
  }
  #undef STAGE

  if (nt < 2) {
    unsigned short* dst = (nt == 0) ? Qb : Kb;
    #pragma unroll
    for (int m = 0; m < 2; ++m) {
      int t0 = mt * 64 + wm * 32 + m * 16 + h4 * 4;
      #pragma unroll
      for (int n = 0; n < 4; ++n) {
        int d = wn * 64 + n * 16 + r16;
        #pragma unroll
        for (int r = 0; r < 4; ++r)
          dst[(size_t)(t0 + r) * ND + d] = f2bf(acc[m][n][r]);
      }
    }
  } else {
    #pragma unroll
    for (int m = 0; m < 2; ++m) {
      int t0 = mt * 64 + wm * 32 + m * 16 + h4 * 4;
      int b = t0 >> 12;
      int tl = t0 & (NT - 1);
      #pragma unroll
      for (int n = 0; n < 4; ++n) {
        int d = wn * 64 + n * 16 + r16;
        u16x4 pk;
        #pragma unroll
        for (int r = 0; r < 4; ++r) pk[r] = f2bf(acc[m][n][r]);
        *(u16x4*)(Vt + (size_t)b * (ND * NT) + (size_t)d * NT + tl) = pk;
      }
    }
  }
}

// ---------------------------------------------------------------------------
// Kernel 3: flash attention v3: double-buffered K/V prefetch.
// Block = 4 waves, wave = 32 q-rows, kv-split = 8, KVBLK = 64.
// LDS: kbuf[2] 32K + vbuf[2] 32K + plds 16K = 80 KB -> 2 blocks/CU.
// Loop: issue STAGE(next) -> compute(cur) -> 1 barrier -> swap.
// plds is [32][64] with 16B-slot XOR swizzle (slot ^= row&7).
// ---------------------------------------------------------------------------
__global__ __launch_bounds__(256, 2)
void attn_kernel(const unsigned short* __restrict__ Qb,
                 const unsigned short* __restrict__ Kb,
                 const unsigned short* __restrict__ Vt,
                 unsigned short* __restrict__ Opart, float* __restrict__ Mpart,
                 float* __restrict__ Lpart) {
  __shared__ unsigned short kbuf[2][64 * 128];   // [krow][d], swizzled
  __shared__ unsigned short vbuf[2][128 * 64];   // [d][t],   swizzled
  __shared__ unsigned short plds[4][2048];       // per-wave P, [32][64] swizzled

  int wave = threadIdx.x >> 6;
  int lane = threadIdx.x & 63;
  int r16 = lane & 15;
  int h4 = lane >> 4;
  int h8 = h4 * 8;

  int b = blockIdx.y;
  int z = blockIdx.z;
  int qb0 = blockIdx.x * 128;
  int kstart = z * KSPAN;
  int kend = min(qb0 + 128, kstart + KSPAN);
  if (kend <= kstart) return;

  int q0 = qb0 + wave * 32;

  const unsigned short* Qbb = Qb + (size_t)b * NT * ND;
  const unsigned short* Kbb = Kb + (size_t)b * NT * ND;
  const unsigned short* Vtb = Vt + (size_t)b * ND * NT;

  bf16x8 qf[2][4];
  #pragma unroll
  for (int f = 0; f < 2; ++f)
    #pragma unroll
    for (int dc = 0; dc < 4; ++dc)
      qf[f][dc] = *(const bf16x8*)(Qbb + (size_t)(q0 + f * 16 + r16) * ND + dc * 32 + h8);

  f32x4 accO[2][8];
  #pragma unroll
  for (int f = 0; f < 2; ++f)
    #pragma unroll
    for (int i = 0; i < 8; ++i) accO[f][i] = (f32x4){0.f, 0.f, 0.f, 0.f};
  float mr[2][4], lr[2][4];
  #pragma unroll
  for (int f = 0; f < 2; ++f)
    #pragma unroll
    for (int r = 0; r < 4; ++r) { mr[f][r] = -1e30f; lr[f][r] = 0.f; }

  // stage K/V tile at key offset kv into buffer bi (all 4 waves cooperate)
  #define STAGE_KV(bi, kv)                                                      \
    {                                                                           \
      _Pragma("unroll")                                                         \
      for (int i = 0; i < 4; ++i) {                                             \
        int e = i * 256 + wave * 64 + lane;                                     \
        int krow = e >> 4, ks = e & 15;                                         \
        const char* gk = (const char*)(Kbb + (size_t)((kv) + krow) * ND)        \
                         + ((ks * 16) ^ ((krow & 7) << 4));                     \
        g2lds16(gk, (char*)kbuf[bi] + (size_t)(i * 256 + wave * 64) * 16);      \
      }                                                                         \
      _Pragma("unroll")                                                         \
      for (int i = 0; i < 4; ++i) {                                             \
        int e = i * 256 + wave * 64 + lane;                                     \
        int vrow = e >> 3, vs = e & 7;                                          \
        const char* gv = (const char*)(Vtb + (size_t)vrow * NT + (kv))          \
                         + ((vs * 16) ^ ((vrow & 7) << 4));                     \
        g2lds16(gv, (char*)vbuf[bi] + (size_t)(i * 256 + wave * 64) * 16);      \
      }                                                                         \
    }

  STAGE_KV(0, kstart);
  __syncthreads();

  int cur = 0;
  for (int kv0 = kstart; kv0 < kend; kv0 += 64) {
    if (kv0 + 64 < kend) STAGE_KV(cur ^ 1, kv0 + 64);

    if (kv0 < q0 + 32) {
      // ---- S = Q K^T ----
      f32x4 s[2][4];
      __builtin_amdgcn_s_setprio(1);
      #pragma unroll
      for (int kt = 0; kt < 4; ++kt) {
        s[0][kt] = (f32x4){0.f, 0.f, 0.f, 0.f};
        s[1][kt] = (f32x4){0.f, 0.f, 0.f, 0.f};
        int krow = kt * 16 + r16;
        #pragma unroll
        for (int dc = 0; dc < 4; ++dc) {
          int off = krow * 256 + ((dc * 64 + h4 * 16) ^ ((krow & 7) << 4));
          bf16x8 kf = *(const bf16x8*)((const char*)kbuf[cur] + off);
          s[0][kt] = __builtin_amdgcn_mfma_f32_16x16x32_bf16(qf[0][dc], kf, s[0][kt], 0, 0, 0);
          s[1][kt] = __builtin_amdgcn_mfma_f32_16x16x32_bf16(qf[1][dc], kf, s[1][kt], 0, 0, 0);
        }
      }
      __builtin_amdgcn_s_setprio(0);

      // ---- mask + tile row-max ----
      float tmax[2][4];
      #pragma unroll
      for (int f = 0; f < 2; ++f)
        #pragma unroll
        for (int r = 0; r < 4; ++r) tmax[f][r] = -3e38f;
      #pragma unroll
      for (int kt = 0; kt < 4; ++kt) {
        int key = kv0 + kt * 16 + r16;
        #pragma unroll
        for (int f = 0; f < 2; ++f)
          #pragma unroll
          for (int r = 0; r < 4; ++r) {
            int q = q0 + f * 16 + h4 * 4 + r;
            float v = (key <= q) ? s[f][kt][r] : -3e38f;
            s[f][kt][r] = v;
            tmax[f][r] = fmaxf(tmax[f][r], v);
          }
      }
      #pragma unroll
      for (int f = 0; f < 2; ++f)
        #pragma unroll
        for (int r = 0; r < 4; ++r)
          #pragma unroll
          for (int msk = 1; msk < 16; msk <<= 1)
            tmax[f][r] = fmaxf(tmax[f][r], __shfl_xor(tmax[f][r], msk, 64));

      // ---- defer-max rescale ----
      bool grow = false;
      #pragma unroll
      for (int f = 0; f < 2; ++f)
        #pragma unroll
        for (int r = 0; r < 4; ++r) grow = grow || (tmax[f][r] > mr[f][r] + 11.0f);
      if (__any(grow)) {
        #pragma unroll
        for (int f = 0; f < 2; ++f) {
          float sf[4];
          #pragma unroll
          for (int r = 0; r < 4; ++r) {
            float mn = fmaxf(mr[f][r], tmax[f][r]);
            sf[r] = EXP2F(mr[f][r] - mn);
            mr[f][r] = mn;
            lr[f][r] *= sf[r];
          }
          #pragma unroll
          for (int dt = 0; dt < 8; ++dt) {
            #pragma unroll
            for (int r = 0; r < 4; ++r) accO[f][dt][r] *= sf[r];
          }
        }
      }

      // ---- P = exp2(S - m); per-lane partial row-sums ----
      #pragma unroll
      for (int kt = 0; kt < 4; ++kt)
        #pragma unroll
        for (int f = 0; f < 2; ++f)
          #pragma unroll
          for (int r = 0; r < 4; ++r) {
            float p = EXP2F(s[f][kt][r] - mr[f][r]);
            s[f][kt][r] = p;
            lr[f][r] += p;
          }

      // ---- P -> LDS ([32][64], 16B-slot XOR swizzle) ----
      #pragma unroll
      for (int kt = 0; kt < 4; ++kt)
        #pragma unroll
        for (int f = 0; f < 2; ++f)
          #pragma unroll
          for (int r = 0; r < 4; ++r) {
            int row = f * 16 + h4 * 4 + r;
            int slot = (kt * 2 + (r16 >> 3)) ^ (row & 7);
            plds[wave][row * 64 + slot * 8 + (r16 & 7)] = f2bf(s[f][kt][r]);
          }

      // ---- O += P V ----
      __builtin_amdgcn_s_setprio(1);
      #pragma unroll
      for (int kc = 0; kc < 2; ++kc) {
        int sl = ((kc * 4 + h4) ^ (r16 & 7)) * 8;
        bf16x8 pf0 = *(const bf16x8*)(&plds[wave][r16 * 64 + sl]);
        bf16x8 pf1 = *(const bf16x8*)(&plds[wave][(16 + r16) * 64 + sl]);
        #pragma unroll
        for (int dt = 0; dt < 8; ++dt) {
          int vrow = dt * 16 + r16;
          int off = vrow * 128 + ((kc * 64 + h4 * 16) ^ ((vrow & 7) << 4));
          bf16x8 vf = *(const bf16x8*)((const char*)vbuf[cur] + off);
          accO[0][dt] = __builtin_amdgcn_mfma_f32_16x16x32_bf16(pf0, vf, accO[0][dt], 0, 0, 0);
          accO[1][dt] = __builtin_amdgcn_mfma_f32_16x16x32_bf16(pf1, vf, accO[1][dt], 0, 0, 0);
        }
      }
      __builtin_amdgcn_s_setprio(0);
    }
    __syncthreads();   // prefetch landed + all reads of cur done
    cur ^= 1;
  }
  #undef STAGE_KV

  // ---- epilogue: reduce l across 16 lanes of each row, write partials ----
  #pragma unroll
  for (int f = 0; f < 2; ++f)
    #pragma unroll
    for (int r = 0; r < 4; ++r)
      #pragma unroll
      for (int msk = 1; msk < 16; msk <<= 1)
        lr[f][r] += __shfl_xor(lr[f][r], msk, 64);

  size_t pbase = ((size_t)z * NBATCH + b) * NT + q0;
  #pragma unroll
  for (int f = 0; f < 2; ++f)
    #pragma unroll
    for (int dt = 0; dt < 8; ++dt)
      #pragma unroll
      for (int r = 0; r < 4; ++r)
        Opart[(pbase + f * 16 + h4 * 4 + r) * ND + dt * 16 + r16] = f2bf(accO[f][dt][r]);
  if (r16 == 0) {
    #pragma unroll
    for (int f = 0; f < 2; ++f)
      #pragma unroll
      for (int r = 0; r < 4; ++r) {
        Mpart[pbase + f * 16 + h4 * 4 + r] = mr[f][r];
        Lpart[pbase + f * 16 + h4 * 4 + r] = lr[f][r];
      }
  }
}

// ---------------------------------------------------------------------------
// Kernel 4: merge valid splits (z <= q/KSPAN) -> final fp32 output
// ---------------------------------------------------------------------------
__global__ void merge_kernel(const unsigned short* __restrict__ Opart,
                             const float* __restrict__ Mpart,
                             const float* __restrict__ Lpart, float* __restrict__ out) {
  int idx = blockIdx.x * blockDim.x + threadIdx.x;  // [0, BT*16)
  int bq = idx >> 4;
  int dg = idx & 15;
  int q = bq & (NT - 1);
  int nz = (q >> 9) + 1;

  float M = -3e38f;
  #pragma unroll
  for (int zz = 0; zz < NSPLIT; ++zz)
    if (zz < nz) M = fmaxf(M, Mpart[(size_t)zz * BT + bq]);

  float denom = 0.f;
  float o[8] = {0.f, 0.f, 0.f, 0.f, 0.f, 0.f, 0.f, 0.f};
  #pragma unroll
  for (int zz = 0; zz < NSPLIT; ++zz) {
    if (zz < nz) {
      float e = EXP2F(Mpart[(size_t)zz * BT + bq] - M);
      denom += e * Lpart[(size_t)zz * BT + bq];
      bf16x8 ov = *(const bf16x8*)(Opart + ((size_t)zz * BT + bq) * ND + dg * 8);
      #pragma unroll
      for (int j = 0; j < 8; ++j) o[j] += e * bf2f((unsigned short)ov[j]);
    }
  }
  float inv = 1.0f / denom;
  f32x4 o0, o1;
  #pragma unroll
  for (int j = 0; j < 4; ++j) { o0[j] = o[j] * inv; o1[j] = o[4 + j] * inv; }
  float* dst = out + (size_t)bq * ND + dg * 8;
  *(f32x4*)dst = o0;
  *(f32x4*)(dst + 4) = o1;
}

// ---------------------------------------------------------------------------
extern "C" void kernel_launch(void* const* d_in, const int* in_sizes, int n_in,
                              void* d_out, int out_size, void* d_ws, size_t ws_size,
                              hipStream_t stream) {
  const float* x  = (const float*)d_in[0];
  const float* Wq = (const float*)d_in[1];
  const float* Wk = (const float*)d_in[2];
  const float* Wv = (const float*)d_in[3];

  char* ws = (char*)d_ws;
  // layout (bytes), total 47185920:
  //   Qb    @ 0        : 4194304
  //   Kb    @ 4194304  : 4194304
  //   Vt    @ 8388608  : 4194304
  //   Opart @ 12582912 : 33554432 (bf16)
  //   Mpart @ 46137344 : 524288
  //   Lpart @ 46661632 : 524288
  //   Wt    @ 12582912 : 786432  (ALIASES Opart: Wt dead before attn writes)
  unsigned short* Qb = (unsigned short*)ws;
  unsigned short* Kb = (unsigned short*)(ws + 4194304);
  unsigned short* Vt = (unsigned short*)(ws + 8388608);
  unsigned short* Opart = (unsigned short*)(ws + 12582912);
  float* Mpart = (float*)(ws + 46137344);
  float* Lpart = (float*)(ws + 46661632);
  unsigned short* Wt = (unsigned short*)(ws + 12582912);

  hipLaunchKernelGGL(wcvt_kernel, dim3(1536), dim3(256), 0, stream, Wq, Wk, Wv, Wt);
  hipLaunchKernelGGL(proj_kernel, dim3(768), dim3(256), 0, stream, x, Wt, Qb, Kb, Vt);
  hipLaunchKernelGGL(attn_kernel, dim3(NT / 128, NBATCH, NSPLIT), dim3(256), 0, stream,
                     Qb, Kb, Vt, Opart, Mpart, Lpart);
  hipLaunchKernelGGL(merge_kernel, dim3(BT * 16 / 256), dim3(256), 0, stream,
                     Opart, Mpart, Lpart, (float*)d_out);
}